// Round 13
// baseline (130.118 us; speedup 1.0000x reference)
//
#include <hip/hip_runtime.h>

#define NN 8
#define HH 512
#define WW 512
#define CC 3
#define KK 5
#define PADP 2
#define WROWF (WW * CC)          // 1536 floats per image row
#define NBLOCKS 4096             // 8 images x 512 rows; block walks 8 wsegs of one row

typedef float f4a __attribute__((ext_vector_type(4), aligned(4)));

struct Row { f4a L0, L1, L2, L3; };   // 15-float window f0..f14 (L3 overlaps at f11)

__device__ __forceinline__ void load_row(const float* rb, Row& r) {
    r.L0 = *(const f4a*)(rb);
    r.L1 = *(const f4a*)(rb + 4);
    r.L2 = *(const f4a*)(rb + 8);
    r.L3 = *(const f4a*)(rb + 11);
}

__device__ __forceinline__ void fma_row(const Row& r, const float* wp,
                                        float& a0, float& a1, float& a2) {
    const float w0 = wp[0], w1 = wp[1], w2 = wp[2], w3 = wp[3], w4 = wp[4];
    a0 = fmaf(r.L0[0], w0, a0); a1 = fmaf(r.L0[1], w0, a1); a2 = fmaf(r.L0[2], w0, a2);
    a0 = fmaf(r.L0[3], w1, a0); a1 = fmaf(r.L1[0], w1, a1); a2 = fmaf(r.L1[1], w1, a2);
    a0 = fmaf(r.L1[2], w2, a0); a1 = fmaf(r.L1[3], w2, a1); a2 = fmaf(r.L2[0], w2, a2);
    a0 = fmaf(r.L2[1], w3, a0); a1 = fmaf(r.L2[2], w3, a1); a2 = fmaf(r.L2[3], w3, a2);
    a0 = fmaf(r.L3[1], w4, a0); a1 = fmaf(r.L3[2], w4, a1); a2 = fmaf(r.L3[3], w4, a2);
}

#define GLDS16(gp, lp) __builtin_amdgcn_global_load_lds( \
    (const __attribute__((address_space(1))) void*)(gp), \
    (__attribute__((address_space(3))) void*)(lp), 16, 0, 0)
#define GLDS4(gp, lp) __builtin_amdgcn_global_load_lds( \
    (const __attribute__((address_space(1))) void*)(gp), \
    (__attribute__((address_space(3))) void*)(lp), 4, 0, 0)

// stage one wseg's 64x25 weights (6400B) into an LDS buffer: exactly 7 VMEM ops
#define STAGE(dst, jj) do {                                             \
    const char* _s = (const char*)(wt + (rowbase + ((long)(jj) << 6)) * (KK * KK)); \
    _Pragma("unroll")                                                   \
    for (int _it = 0; _it < 6; ++_it)                                   \
        GLDS16(_s + _it * 1024 + lane * 16, (dst) + _it * 256);         \
    GLDS4(_s + 6144 + lane * 4, (dst) + 1536);                         \
} while (0)

// counted wait: everything OLDER than the newest N vmem ops is complete
#define WAITK(N) do {                                                   \
    asm volatile("s_waitcnt vmcnt(" #N ")" ::: "memory");               \
    __builtin_amdgcn_sched_barrier(0);                                  \
} while (0)

// load the 5-row input window for wseg jj (clamped cols; exactly 20 VMEM ops)
#define LOADIN(jj) do {                                                 \
    int _wc = ((jj) << 6) + lane - PADP;                                \
    _wc = _wc < 0 ? 0 : (_wc > 507 ? 507 : _wc);                        \
    const float* _rb = inb + (long)(h - PADP) * WROWF + _wc * CC;       \
    load_row(_rb + 0 * WROWF, R0);                                      \
    load_row(_rb + 1 * WROWF, R1);                                      \
    load_row(_rb + 2 * WROWF, R2);                                      \
    load_row(_rb + 3 * WROWF, R3);                                      \
    load_row(_rb + 4 * WROWF, R4);                                      \
} while (0)

// interior compute for wseg jj from buffer BUF + exec-masked border-lane fixup
#define COMPUTE(BUF, jj) do {                                           \
    const float* _wp = &(BUF)[lane * (KK * KK)];                        \
    float a0 = 0.f, a1 = 0.f, a2 = 0.f;                                 \
    fma_row(R0, _wp + 0,  a0, a1, a2);                                  \
    fma_row(R1, _wp + 5,  a0, a1, a2);                                  \
    fma_row(R2, _wp + 10, a0, a1, a2);                                  \
    fma_row(R3, _wp + 15, a0, a1, a2);                                  \
    fma_row(R4, _wp + 20, a0, a1, a2);                                  \
    const int _w = ((jj) << 6) + lane;                                  \
    if (_w < PADP || _w >= WW - PADP) {     /* live only on wseg 0 / 7 */ \
        a0 = 0.f; a1 = 0.f; a2 = 0.f;                                   \
        _Pragma("unroll")                                               \
        for (int dh = 0; dh < KK; ++dh) {                               \
            const int ih = h + dh - PADP;                               \
            _Pragma("unroll")                                           \
            for (int dw = 0; dw < KK; ++dw) {                           \
                const int iw = _w + dw - PADP;                          \
                const bool ok = ((unsigned)iw < (unsigned)WW);          \
                const float* p = inb + ((long)ih * WW + iw) * CC;       \
                float v0 = ok ? p[0] : 0.f;                             \
                float v1 = ok ? p[1] : 0.f;                             \
                float v2 = ok ? p[2] : 0.f;                             \
                const float wv = _wp[dh * KK + dw];                     \
                a0 = fmaf(v0, wv, a0);                                  \
                a1 = fmaf(v1, wv, a1);                                  \
                a2 = fmaf(v2, wv, a2);                                  \
            }                                                           \
        }                                                               \
    }                                                                   \
    float* _o = out + (rowbase + _w) * CC;                              \
    _o[0] = a0; _o[1] = a1; _o[2] = a2;                                 \
} while (0)

// border-row compute (h in {0,1,510,511}): fully predicated scalar, weights from LDS
#define SCALAR(BUF, jj) do {                                            \
    const float* _wp = &(BUF)[lane * (KK * KK)];                        \
    const int _w = ((jj) << 6) + lane;                                  \
    float a0 = 0.f, a1 = 0.f, a2 = 0.f;                                 \
    _Pragma("unroll")                                                   \
    for (int dh = 0; dh < KK; ++dh) {                                   \
        const int ih = h + dh - PADP;                                   \
        const bool rok = ((unsigned)ih < (unsigned)HH);                 \
        _Pragma("unroll")                                               \
        for (int dw = 0; dw < KK; ++dw) {                               \
            const int iw = _w + dw - PADP;                              \
            const bool ok = rok && ((unsigned)iw < (unsigned)WW);       \
            const float* p = inb + ((long)ih * WW + iw) * CC;           \
            float v0 = ok ? p[0] : 0.f;                                 \
            float v1 = ok ? p[1] : 0.f;                                 \
            float v2 = ok ? p[2] : 0.f;                                 \
            const float wv = _wp[dh * KK + dw];                         \
            a0 = fmaf(v0, wv, a0);                                      \
            a1 = fmaf(v1, wv, a1);                                      \
            a2 = fmaf(v2, wv, a2);                                      \
        }                                                               \
    }                                                                   \
    float* _o = out + (rowbase + _w) * CC;                              \
    _o[0] = a0; _o[1] = a1; _o[2] = a2;                                 \
} while (0)

__global__ __launch_bounds__(64, 3) void conv_local_kernel(
    const float* __restrict__ in,   // (N,H,W,C)
    const float* __restrict__ wt,   // (N,H,W,25)
    float* __restrict__ out)        // (N,H,W,C)
{
    __shared__ float bufA[64 * KK * KK];   // 6.4 KB
    __shared__ float bufB[64 * KK * KK];   // 6.4 KB -> 12.8 KB, 12 blocks/CU

    const int lane = threadIdx.x;
    // bijective XCD swizzle: 4096 = 8 x 512; XCD k streams image k's weights
    // linearly (block = one row; consecutive blocks = consecutive rows).
    const int b = ((blockIdx.x & 7) << 9) | (blockIdx.x >> 3);
    const int n = b >> 9;
    const int h = b & (HH - 1);
    const long rowbase = (long)(n * HH + h) * WW;

    const float* inb = in + (size_t)n * (HH * WW * CC);
    const bool rowok = (h >= PADP) && (h < HH - PADP);

    float* cur = bufA;
    float* nxt = bufB;

    STAGE(cur, 0);                         // prologue: wseg0 weights in flight

    if (rowok) {
        Row R0, R1, R2, R3, R4;
        LOADIN(0);
#pragma unroll 1
        for (int j = 0; j < 7; ++j) {
            STAGE(nxt, j + 1);             // next wseg's weights in flight
            WAITK(7);                      // drain cur-stage + input + stores; keep nxt
            COMPUTE(cur, j);
            LOADIN(j + 1);                 // rows consumed; reload for next wseg
            float* t = cur; cur = nxt; nxt = t;
        }
        WAITK(0);
        COMPUTE(cur, 7);
    } else {
        // border rows (h in {0,1,510,511}): same weight pipeline, scalar compute
#pragma unroll 1
        for (int j = 0; j < 7; ++j) {
            STAGE(nxt, j + 1);
            WAITK(7);
            SCALAR(cur, j);
            float* t = cur; cur = nxt; nxt = t;
        }
        WAITK(0);
        SCALAR(cur, 7);
    }
}

extern "C" void kernel_launch(void* const* d_in, const int* in_sizes, int n_in,
                              void* d_out, int out_size, void* d_ws, size_t ws_size,
                              hipStream_t stream) {
    const float* in = (const float*)d_in[0];   // (8,512,512,3) f32
    const float* wt = (const float*)d_in[1];   // (8,512,512,25) f32
    float* out = (float*)d_out;                // (8,512,512,3) f32

    conv_local_kernel<<<NBLOCKS, 64, 0, stream>>>(in, wt, out);
}

// Round 14
// 63.130 us; speedup vs baseline: 2.0611x; 2.0611x over previous
//
#include <hip/hip_runtime.h>

#define NN 8
#define HH 512
#define WW 512
#define CC 3
#define KK 5
#define PADP 2
#define WROWF (WW * CC)          // 1536 floats per image row
#define NBLOCKS 4096             // (n, h-pair, half): 8 * 256 * 2; block walks 4 wsegs

typedef float f4a __attribute__((ext_vector_type(4), aligned(4)));

struct Row { f4a L0, L1, L2, L3; };   // 15-float window f0..f14 (L3 overlaps at f11)

__device__ __forceinline__ void load_row(const float* rb, Row& r) {
    r.L0 = *(const f4a*)(rb);
    r.L1 = *(const f4a*)(rb + 4);
    r.L2 = *(const f4a*)(rb + 8);
    r.L3 = *(const f4a*)(rb + 11);
}

__device__ __forceinline__ void fma_row(const Row& r, const float* wp,
                                        float& a0, float& a1, float& a2) {
    const float w0 = wp[0], w1 = wp[1], w2 = wp[2], w3 = wp[3], w4 = wp[4];
    a0 = fmaf(r.L0[0], w0, a0); a1 = fmaf(r.L0[1], w0, a1); a2 = fmaf(r.L0[2], w0, a2);
    a0 = fmaf(r.L0[3], w1, a0); a1 = fmaf(r.L1[0], w1, a1); a2 = fmaf(r.L1[1], w1, a2);
    a0 = fmaf(r.L1[2], w2, a0); a1 = fmaf(r.L1[3], w2, a1); a2 = fmaf(r.L2[0], w2, a2);
    a0 = fmaf(r.L2[1], w3, a0); a1 = fmaf(r.L2[2], w3, a1); a2 = fmaf(r.L2[3], w3, a2);
    a0 = fmaf(r.L3[1], w4, a0); a1 = fmaf(r.L3[2], w4, a1); a2 = fmaf(r.L3[3], w4, a2);
}

#define GLDS16(gp, lp) __builtin_amdgcn_global_load_lds( \
    (const __attribute__((address_space(1))) void*)(gp), \
    (__attribute__((address_space(3))) void*)(lp), 16, 0, 0)
#define GLDS4(gp, lp) __builtin_amdgcn_global_load_lds( \
    (const __attribute__((address_space(1))) void*)(gp), \
    (__attribute__((address_space(3))) void*)(lp), 4, 0, 0)

// stage BOTH rows' weights for wseg jj into buffers d0,d1: exactly 14 VMEM ops
#define STAGE2(d0, d1, jj) do {                                          \
    const long _p = (long)(nHH + h0) * WW + (((half << 2) | (jj)) << 6); \
    const char* _s0 = (const char*)(wt + _p * (KK * KK));                \
    const char* _s1 = (const char*)(wt + (_p + WW) * (KK * KK));         \
    _Pragma("unroll")                                                    \
    for (int _it = 0; _it < 6; ++_it)                                    \
        GLDS16(_s0 + _it * 1024 + lane * 16, (d0) + _it * 256);          \
    GLDS4(_s0 + 6144 + lane * 4, (d0) + 1536);                           \
    _Pragma("unroll")                                                    \
    for (int _it = 0; _it < 6; ++_it)                                    \
        GLDS16(_s1 + _it * 1024 + lane * 16, (d1) + _it * 256);          \
    GLDS4(_s1 + 6144 + lane * 4, (d1) + 1536);                           \
} while (0)

// counted wait: everything OLDER than the newest N vmem ops is complete
#define WAITK(N) do {                                                    \
    asm volatile("s_waitcnt vmcnt(" #N ")" ::: "memory");                \
    __builtin_amdgcn_sched_barrier(0);                                   \
} while (0)

__global__ __launch_bounds__(64, 4) void conv_local_kernel(
    const float* __restrict__ in,   // (N,H,W,C)
    const float* __restrict__ wt,   // (N,H,W,25)
    float* __restrict__ out)        // (N,H,W,C)
{
    __shared__ float bA0[1600], bA1[1600];   // pair 0: 12.8 KB
    __shared__ float bB0[1600], bB1[1600];   // pair 1: 12.8 KB  -> 25.6 KB total

    const int lane = threadIdx.x;
    // bijective XCD swizzle: 4096 = 8 x 512; XCD k streams image k's weights
    const int b    = ((blockIdx.x & 7) << 9) | (blockIdx.x >> 3);
    const int n    = b >> 9;
    const int rem  = b & 511;
    const int hp   = rem >> 1;          // 0..255
    const int half = rem & 1;           // walks wsegs half*4 .. half*4+3
    const int h0   = hp << 1;           // 0..510 (rows h0, h0+1)
    const int nHH  = n * HH;

    const float* inb  = in + (size_t)n * (HH * WW * CC);
    const bool  rowok = (hp >= 1) && (hp <= 254);

    float* c0 = bA0; float* c1 = bA1;   // current step's weight pair
    float* n0 = bB0; float* n1 = bB1;   // next step's weight pair

    STAGE2(c0, c1, 0);                  // prologue: step-0 weights in flight

#pragma unroll 1
    for (int j = 0; j < 4; ++j) {
        const int  w0 = (((half << 2) | j)) << 6;
        const long p0 = (long)(nHH + h0) * WW + w0;
        const long p1 = p0 + WW;
        const bool wfast = rowok && (w0 != 0) && (w0 != WW - 64);

        Row R0, R1, R2, R3, R4, R5;
        if (wfast) {
            // inputs at step START: latency overlaps the weight wait (R13 fix)
            const float* rb = inb + ((long)(h0 - PADP) * WW + (w0 + lane - PADP)) * CC;
            load_row(rb + 0 * WROWF, R0);
            load_row(rb + 1 * WROWF, R1);
            load_row(rb + 2 * WROWF, R2);
            load_row(rb + 3 * WROWF, R3);
            load_row(rb + 4 * WROWF, R4);
            load_row(rb + 5 * WROWF, R5);
        }
        if (j < 3) {
            STAGE2(n0, n1, j + 1);      // next step's weights in flight across compute
            WAITK(14);                  // drain cur weights + inputs + old stores; keep next stage
        } else {
            WAITK(0);
        }

        const float* wp0 = &c0[lane * (KK * KK)];
        const float* wp1 = &c1[lane * (KK * KK)];

        if (wfast) {
            float a0 = 0.f, a1 = 0.f, a2 = 0.f;   // px (h0,   w)
            float d0 = 0.f, d1 = 0.f, d2 = 0.f;   // px (h0+1, w)
            fma_row(R0, wp0 + 0,  a0, a1, a2);
            fma_row(R1, wp0 + 5,  a0, a1, a2);
            fma_row(R1, wp1 + 0,  d0, d1, d2);
            fma_row(R2, wp0 + 10, a0, a1, a2);
            fma_row(R2, wp1 + 5,  d0, d1, d2);
            fma_row(R3, wp0 + 15, a0, a1, a2);
            fma_row(R3, wp1 + 10, d0, d1, d2);
            fma_row(R4, wp0 + 20, a0, a1, a2);
            fma_row(R4, wp1 + 15, d0, d1, d2);
            fma_row(R5, wp1 + 20, d0, d1, d2);

            float* o0 = out + (p0 + lane) * CC;
            o0[0] = a0; o0[1] = a1; o0[2] = a2;
            float* o1 = out + (p1 + lane) * CC;
            o1[0] = d0; o1[1] = d1; o1[2] = d2;
        } else {
            // border step: predicated scalar path (R1-proven), weights from LDS
#pragma unroll
            for (int px = 0; px < 2; ++px) {
                const int hh = h0 + px;
                const int w  = w0 + lane;
                const float* wp = px ? wp1 : wp0;
                float a0 = 0.f, a1 = 0.f, a2 = 0.f;
#pragma unroll
                for (int dh = 0; dh < KK; ++dh) {
                    const int ih = hh + dh - PADP;
                    const bool rok = ((unsigned)ih < (unsigned)HH);
#pragma unroll
                    for (int dw = 0; dw < KK; ++dw) {
                        const int iw = w + dw - PADP;
                        const bool ok = rok && ((unsigned)iw < (unsigned)WW);
                        const float* p = inb + ((long)(ih * WW + iw)) * CC;
                        float v0 = ok ? p[0] : 0.f;
                        float v1 = ok ? p[1] : 0.f;
                        float v2 = ok ? p[2] : 0.f;
                        const float wv = wp[dh * KK + dw];
                        a0 = fmaf(v0, wv, a0);
                        a1 = fmaf(v1, wv, a1);
                        a2 = fmaf(v2, wv, a2);
                    }
                }
                float* o = out + ((long)(nHH + hh) * WW + w) * CC;
                o[0] = a0; o[1] = a1; o[2] = a2;
            }
        }

        // rotate buffer pairs
        float* t;
        t = c0; c0 = n0; n0 = t;
        t = c1; c1 = n1; n1 = t;
    }
}

extern "C" void kernel_launch(void* const* d_in, const int* in_sizes, int n_in,
                              void* d_out, int out_size, void* d_ws, size_t ws_size,
                              hipStream_t stream) {
    const float* in = (const float*)d_in[0];   // (8,512,512,3) f32
    const float* wt = (const float*)d_in[1];   // (8,512,512,25) f32
    float* out = (float*)d_out;                // (8,512,512,3) f32

    conv_local_kernel<<<NBLOCKS, 64, 0, stream>>>(in, wt, out);
}

// Round 15
// 60.229 us; speedup vs baseline: 2.1604x; 1.0482x over previous
//
#include <hip/hip_runtime.h>

#define NN 8
#define HH 512
#define WW 512
#define CC 3
#define KK 5
#define PADP 2
#define WROWF (WW * CC)          // 1536 floats per image row
#define NBLOCKS 8192             // 8 img x 512 rows x 2 halves; block walks 4 wsegs

typedef float f4a __attribute__((ext_vector_type(4), aligned(4)));

struct Row { f4a L0, L1, L2, L3; };   // 15-float window f0..f14 (L3 overlaps at f11)

__device__ __forceinline__ void load_row(const float* rb, Row& r) {
    r.L0 = *(const f4a*)(rb);
    r.L1 = *(const f4a*)(rb + 4);
    r.L2 = *(const f4a*)(rb + 8);
    r.L3 = *(const f4a*)(rb + 11);
}

__device__ __forceinline__ void fma_row(const Row& r, const float* wp,
                                        float& a0, float& a1, float& a2) {
    const float w0 = wp[0], w1 = wp[1], w2 = wp[2], w3 = wp[3], w4 = wp[4];
    a0 = fmaf(r.L0[0], w0, a0); a1 = fmaf(r.L0[1], w0, a1); a2 = fmaf(r.L0[2], w0, a2);
    a0 = fmaf(r.L0[3], w1, a0); a1 = fmaf(r.L1[0], w1, a1); a2 = fmaf(r.L1[1], w1, a2);
    a0 = fmaf(r.L1[2], w2, a0); a1 = fmaf(r.L1[3], w2, a1); a2 = fmaf(r.L2[0], w2, a2);
    a0 = fmaf(r.L2[1], w3, a0); a1 = fmaf(r.L2[2], w3, a1); a2 = fmaf(r.L2[3], w3, a2);
    a0 = fmaf(r.L3[1], w4, a0); a1 = fmaf(r.L3[2], w4, a1); a2 = fmaf(r.L3[3], w4, a2);
}

#define GLDS16(gp, lp) __builtin_amdgcn_global_load_lds( \
    (const __attribute__((address_space(1))) void*)(gp), \
    (__attribute__((address_space(3))) void*)(lp), 16, 0, 0)
#define GLDS4(gp, lp) __builtin_amdgcn_global_load_lds( \
    (const __attribute__((address_space(1))) void*)(gp), \
    (__attribute__((address_space(3))) void*)(lp), 4, 0, 0)

// stage one wseg's 64x25 weights (6400B) into the LDS buffer: exactly 7 VMEM ops
#define STAGE(jj) do {                                                  \
    const long _p = rowpix + (((half << 2) | (jj)) << 6);               \
    const char* _s = (const char*)(wt + _p * (KK * KK));                \
    _Pragma("unroll")                                                   \
    for (int _it = 0; _it < 6; ++_it)                                   \
        GLDS16(_s + _it * 1024 + lane * 16, wbuf + _it * 256);          \
    GLDS4(_s + 6144 + lane * 4, wbuf + 1536);                          \
} while (0)

#define WAITV0() do {                                                   \
    asm volatile("s_waitcnt vmcnt(0)" ::: "memory");                    \
    __builtin_amdgcn_sched_barrier(0);                                  \
} while (0)

// ds_reads of the current weights complete -> safe to overwrite the buffer
#define LGKM0() do {                                                    \
    asm volatile("s_waitcnt lgkmcnt(0)" ::: "memory");                  \
    __builtin_amdgcn_sched_barrier(0);                                  \
} while (0)

__global__ __launch_bounds__(64, 4) void conv_local_kernel(
    const float* __restrict__ in,   // (N,H,W,C)
    const float* __restrict__ wt,   // (N,H,W,25)
    float* __restrict__ out)        // (N,H,W,C)
{
    __shared__ float wbuf[64 * KK * KK];   // single 6.4 KB buffer -> 16 blocks/CU (WG cap)

    const int lane = threadIdx.x;
    // bijective XCD swizzle: 8192 = 8 x 1024; XCD k streams image k's weights
    const int b    = ((blockIdx.x & 7) << 10) | (blockIdx.x >> 3);
    const int n    = b >> 10;
    const int rem  = b & 1023;
    const int h    = rem >> 1;          // 0..511
    const int half = rem & 1;           // walks wsegs half*4 .. half*4+3
    const long rowpix = (long)(n * HH + h) * WW;

    const float* inb  = in + (size_t)n * (HH * WW * CC);
    const bool  rowok = (h >= PADP) && (h < HH - PADP);

    STAGE(0);                           // prologue: step-0 weights in flight

#pragma unroll 1
    for (int j = 0; j < 4; ++j) {
        const int  w0 = (((half << 2) | j)) << 6;
        const long p0 = rowpix + w0;
        const bool wfast = rowok && (w0 != 0) && (w0 != WW - 64);

        if (wfast) {
            // inputs at step start: their latency hides under the weight drain
            const float* rb = inb + ((long)(h - PADP) * WW + (w0 + lane - PADP)) * CC;
            Row R0, R1, R2, R3, R4;
            load_row(rb + 0 * WROWF, R0);
            load_row(rb + 1 * WROWF, R1);
            load_row(rb + 2 * WROWF, R2);
            load_row(rb + 3 * WROWF, R3);
            load_row(rb + 4 * WROWF, R4);
            WAITV0();                   // weights (oldest) + inputs complete

            const float* wp = &wbuf[lane * (KK * KK)];
            float a0 = 0.f, a1 = 0.f, a2 = 0.f;
            fma_row(R0, wp + 0,  a0, a1, a2);
            fma_row(R1, wp + 5,  a0, a1, a2);
            fma_row(R2, wp + 10, a0, a1, a2);
            fma_row(R3, wp + 15, a0, a1, a2);
            fma_row(R4, wp + 20, a0, a1, a2);

            float* o = out + (p0 + lane) * CC;
            o[0] = a0; o[1] = a1; o[2] = a2;
        } else {
            WAITV0();
            // border step: predicated scalar path (R1-proven), weights from LDS
            const float* wp = &wbuf[lane * (KK * KK)];
            const int w = w0 + lane;
            float a0 = 0.f, a1 = 0.f, a2 = 0.f;
#pragma unroll
            for (int dh = 0; dh < KK; ++dh) {
                const int ih = h + dh - PADP;
                const bool rok = ((unsigned)ih < (unsigned)HH);
#pragma unroll
                for (int dw = 0; dw < KK; ++dw) {
                    const int iw = w + dw - PADP;
                    const bool ok = rok && ((unsigned)iw < (unsigned)WW);
                    const float* p = inb + ((long)(ih * WW + iw)) * CC;
                    float v0 = ok ? p[0] : 0.f;
                    float v1 = ok ? p[1] : 0.f;
                    float v2 = ok ? p[2] : 0.f;
                    const float wv = wp[dh * KK + dw];
                    a0 = fmaf(v0, wv, a0);
                    a1 = fmaf(v1, wv, a1);
                    a2 = fmaf(v2, wv, a2);
                }
            }
            float* o = out + (p0 + lane) * CC;
            o[0] = a0; o[1] = a1; o[2] = a2;
        }

        if (j < 3) {
            LGKM0();                    // current weights fully read from LDS
            STAGE(j + 1);               // reuse the single buffer for the next wseg
        }
    }
}

extern "C" void kernel_launch(void* const* d_in, const int* in_sizes, int n_in,
                              void* d_out, int out_size, void* d_ws, size_t ws_size,
                              hipStream_t stream) {
    const float* in = (const float*)d_in[0];   // (8,512,512,3) f32
    const float* wt = (const float*)d_in[1];   // (8,512,512,25) f32
    float* out = (float*)d_out;                // (8,512,512,3) f32

    conv_local_kernel<<<NBLOCKS, 64, 0, stream>>>(in, wt, out);
}